// Round 11
// baseline (170.287 us; speedup 1.0000x reference)
//
#include <hip/hip_runtime.h>
#include <hip/hip_cooperative_groups.h>
#include <stdint.h>

namespace cg = cooperative_groups;

// N=M=8192, D=DV=128, fp32 in/out. bf16-MFMA flash attention.
// R11: occupancy-guarded cooperative fusion (runtime nsplit 12/8) with
//      guaranteed fallback to the proven R9 4-dispatch path.
#define NQ 8192
#define NM 8192
#define DD 128
#define DVD 128
#define NQB 64                 // 8192/128 q-blocks
#define NSPLX 12               // max spans (workspace sizing)

typedef float f32x4 __attribute__((ext_vector_type(4)));
typedef short s16x8 __attribute__((ext_vector_type(8)));
typedef __fp16 fp16x2 __attribute__((ext_vector_type(2)));
union FragU { uint32_t u[4]; s16x8 v; };
union H2U { fp16x2 h; uint32_t u; };

__device__ __forceinline__ uint32_t bf16rne(float x) {
  uint32_t u = __float_as_uint(x);
  return (u + 0x7FFFu + ((u >> 16) & 1u)) >> 16;
}
__device__ __forceinline__ uint32_t pk2(float a, float b) {
  return __builtin_amdgcn_perm(__float_as_uint(b) + 0x8000u,
                               __float_as_uint(a) + 0x8000u, 0x07060302u);
}
__device__ __forceinline__ void glds16(const void* g, void* l) {
  __builtin_amdgcn_global_load_lds((const __attribute__((address_space(1))) uint32_t*)g,
                                   (__attribute__((address_space(3))) uint32_t*)l, 16, 0, 0);
}

// ---- workspace layout (bytes) ----
#define SZ_MASK ((size_t)(NM / 64) * NQ * 8)   // 8 MB: uint2 per (kb64, q)
#define OFF_K   (SZ_MASK)
#define SZ_KB   ((size_t)NM * DD * 2)          // 2 MB swizzled bf16 K tiles
#define OFF_V   (OFF_K + SZ_KB)                // 2 MB swizzled bf16 V^T tiles
#define OFF_OP  (OFF_V + SZ_KB)
#define SZ_OPH  ((size_t)NQ * DVD * 2)         // fp16 partial O per span
#define OFF_L   (OFF_OP + (size_t)NSPLX * SZ_OPH)

// ====================== shared device routines ======================
struct AttnPtrs {
  const float* Q;
  const uint8_t* Kswz;
  const uint8_t* Vtswz;
  const unsigned int* maskT;
  __fp16* Opart;
  float* lsum;
};

// Full attn body for one (qblk, span). smem = 40960B: K 0..16K | V 16K..32K | Psc 32K..40K.
__device__ __forceinline__ void attn_body(const AttnPtrs& P, uint8_t* smem,
                                          int tid, int qblk, int span, int kb0,
                                          int niter) {
  const int wid = tid >> 6, lane = tid & 63;
  const int g = lane >> 4, qi = lane & 15;
  const int qw = qblk * 128 + wid * 32;

  const float SC = 0.08838834764831845f * 1.4426950408889634f;  // 1/sqrt(128)*log2e

  s16x8 qfrag[2][4];
#pragma unroll
  for (int qt = 0; qt < 2; ++qt)
#pragma unroll
    for (int ks = 0; ks < 4; ++ks) {
      const float* qs = P.Q + (size_t)(qw + 16 * qt + qi) * DD + 32 * ks + 8 * g;
      float4 a = *(const float4*)qs, b = *(const float4*)(qs + 4);
      FragU fu;
      fu.u[0] = bf16rne(a.x * SC) | (bf16rne(a.y * SC) << 16);
      fu.u[1] = bf16rne(a.z * SC) | (bf16rne(a.w * SC) << 16);
      fu.u[2] = bf16rne(b.x * SC) | (bf16rne(b.y * SC) << 16);
      fu.u[3] = bf16rne(b.z * SC) | (bf16rne(b.w * SC) << 16);
      qfrag[qt][ks] = fu.v;
    }

  f32x4 accO[8][2];
#pragma unroll
  for (int dt = 0; dt < 8; ++dt)
#pragma unroll
    for (int qt = 0; qt < 2; ++qt) accO[dt][qt] = (f32x4)0.f;
  f32x4 accL[2] = {(f32x4)0.f, (f32x4)0.f};
  const f32x4 z4 = (f32x4)0.f;

  FragU onesu;
  onesu.u[0] = onesu.u[1] = onesu.u[2] = onesu.u[3] = 0x3F803F80u;
  const s16x8 onesfrag = onesu.v;

  const s16x8* Kv = (const s16x8*)smem;
  const s16x8* Vv = (const s16x8*)(smem + 16384);
  const s16x8* kp[4];
#pragma unroll
  for (int ks = 0; ks < 4; ++ks) kp[ks] = Kv + qi * 16 + ((g + 4 * ks) ^ qi);
  const s16x8* vp[2];
#pragma unroll
  for (int kh = 0; kh < 2; ++kh) vp[kh] = Vv + qi * 8 + ((4 * kh + g) ^ (qi & 7));
  uint32_t* pw = (uint32_t*)(smem + 32768) + (wid * 16 + qi) * 32;
  uint32_t* wr[4];
#pragma unroll
  for (int kt = 0; kt < 4; ++kt) wr[kt] = &pw[2 * ((4 * kt + g) ^ qi)];
  const uint32_t* rd[4];
#pragma unroll
  for (int kh = 0; kh < 2; ++kh)
#pragma unroll
    for (int hb = 0; hb < 2; ++hb) rd[2 * kh + hb] = &pw[2 * ((8 * kh + 2 * g + hb) ^ qi)];

  const uint8_t* ktp = P.Kswz + (size_t)kb0 * 16384 + (size_t)tid * 16;
  const uint8_t* vtp = P.Vtswz + (size_t)kb0 * 16384 + (size_t)tid * 16;
  uint8_t* kld = smem + wid * 1024;
  uint8_t* vld = smem + 16384 + wid * 1024;
  const uint2* mp0 = (const uint2*)P.maskT + (size_t)kb0 * NQ + qw + qi;
  const uint2* mp1 = mp0 + 16;

  for (int it = 0; it < niter; ++it) {
    __syncthreads();
#pragma unroll
    for (int s = 0; s < 4; ++s) {
      glds16(ktp + s * 4096, kld + s * 4096);
      glds16(vtp + s * 4096, vld + s * 4096);
    }
    uint2 wm0 = *mp0, wm1 = *mp1;
    ktp += 16384; vtp += 16384; mp0 += NQ; mp1 += NQ;
    __syncthreads();

    f32x4 sf[2][4];
#pragma unroll
    for (int kt = 0; kt < 4; ++kt) {
      {
        s16x8 kf = kp[0][kt * 256];
        sf[0][kt] = __builtin_amdgcn_mfma_f32_16x16x32_bf16(kf, qfrag[0][0], z4, 0, 0, 0);
        sf[1][kt] = __builtin_amdgcn_mfma_f32_16x16x32_bf16(kf, qfrag[1][0], z4, 0, 0, 0);
      }
#pragma unroll
      for (int ks = 1; ks < 4; ++ks) {
        s16x8 kf = kp[ks][kt * 256];
        sf[0][kt] = __builtin_amdgcn_mfma_f32_16x16x32_bf16(kf, qfrag[0][ks], sf[0][kt], 0, 0, 0);
        sf[1][kt] = __builtin_amdgcn_mfma_f32_16x16x32_bf16(kf, qfrag[1][ks], sf[1][kt], 0, 0, 0);
      }
    }

    if (__ballot((wm0.x | wm0.y | wm1.x | wm1.y) != 0)) {
#pragma unroll
      for (int qt = 0; qt < 2; ++qt) {
        uint2 wm = qt ? wm1 : wm0;
#pragma unroll
        for (int kt = 0; kt < 4; ++kt)
#pragma unroll
          for (int r = 0; r < 4; ++r) {
            int kl = 16 * kt + 4 * g + r;
            unsigned int w = (kl & 32) ? wm.y : wm.x;
            if ((w >> (kl & 31)) & 1u) sf[qt][kt][r] = -3.0e38f;
          }
      }
    }

    s16x8 pfrag[2][2];
#pragma unroll
    for (int qt = 0; qt < 2; ++qt) {
#pragma unroll
      for (int kt = 0; kt < 4; ++kt) {
        float p0 = __builtin_amdgcn_exp2f(sf[qt][kt][0]);
        float p1 = __builtin_amdgcn_exp2f(sf[qt][kt][1]);
        float p2 = __builtin_amdgcn_exp2f(sf[qt][kt][2]);
        float p3 = __builtin_amdgcn_exp2f(sf[qt][kt][3]);
        uint2 pk;
        pk.x = pk2(p0, p1);
        pk.y = pk2(p2, p3);
        *(uint2*)wr[kt] = pk;
      }
      FragU pf0, pf1;
      uint2 a0 = *(const uint2*)rd[0];
      uint2 b0 = *(const uint2*)rd[1];
      uint2 a1 = *(const uint2*)rd[2];
      uint2 b1 = *(const uint2*)rd[3];
      pf0.u[0] = a0.x; pf0.u[1] = a0.y; pf0.u[2] = b0.x; pf0.u[3] = b0.y;
      pf1.u[0] = a1.x; pf1.u[1] = a1.y; pf1.u[2] = b1.x; pf1.u[3] = b1.y;
      pfrag[qt][0] = pf0.v;
      pfrag[qt][1] = pf1.v;
    }

#pragma unroll
    for (int kh = 0; kh < 2; ++kh) {
      accL[0] = __builtin_amdgcn_mfma_f32_16x16x32_bf16(onesfrag, pfrag[0][kh], accL[0], 0, 0, 0);
      accL[1] = __builtin_amdgcn_mfma_f32_16x16x32_bf16(onesfrag, pfrag[1][kh], accL[1], 0, 0, 0);
    }

#pragma unroll
    for (int dt = 0; dt < 8; ++dt) {
#pragma unroll
      for (int kh = 0; kh < 2; ++kh) {
        s16x8 vf = vp[kh][dt * 128];
        accO[dt][0] = __builtin_amdgcn_mfma_f32_16x16x32_bf16(vf, pfrag[0][kh], accO[dt][0], 0, 0, 0);
        accO[dt][1] = __builtin_amdgcn_mfma_f32_16x16x32_bf16(vf, pfrag[1][kh], accO[dt][1], 0, 0, 0);
      }
    }
  }

#pragma unroll
  for (int qt = 0; qt < 2; ++qt) {
    int q = qw + 16 * qt + qi;
#pragma unroll
    for (int dt = 0; dt < 8; ++dt) {
      H2U h0, h1;
      h0.h = __builtin_amdgcn_cvt_pkrtz(accO[dt][qt][0], accO[dt][qt][1]);
      h1.h = __builtin_amdgcn_cvt_pkrtz(accO[dt][qt][2], accO[dt][qt][3]);
      uint2 st = {h0.u, h1.u};
      *(uint2*)(P.Opart + ((size_t)span * NQ + q) * DVD + 16 * dt + 4 * g) = st;
    }
    if (g == 0) P.lsum[(size_t)span * NQ + q] = accL[qt][0];
  }
}

// conv virtual block vb in [0,768): 0..511 K, 512..639 V, 640..767 mask clear
__device__ __forceinline__ void conv_vblock(int vb, int tid, const float* K,
                                            const float* V, uint8_t* Kswz,
                                            uint8_t* Vtswz, unsigned int* maskT,
                                            uint8_t* smem) {
  if (vb < 512) {
    int t = vb * 256 + tid;
    int key = t >> 4, c = t & 15;
    const float* s = K + (size_t)key * DD + 8 * c;
    float4 a = *(const float4*)s, bb = *(const float4*)(s + 4);
    uint4 d;
    d.x = bf16rne(a.x) | (bf16rne(a.y) << 16);
    d.y = bf16rne(a.z) | (bf16rne(a.w) << 16);
    d.z = bf16rne(bb.x) | (bf16rne(bb.y) << 16);
    d.w = bf16rne(bb.z) | (bf16rne(bb.w) << 16);
    size_t off = (size_t)(key >> 6) * 16384 + (size_t)(key & 63) * 256 +
                 (size_t)((c ^ (key & 15)) << 4);
    *(uint4*)(Kswz + off) = d;
  } else if (vb < 640) {
    float(*Vf)[132] = (float(*)[132])smem;  // 33792 B
    int kb = vb - 512;
#pragma unroll
    for (int i = 0; i < 8; ++i) {
      int idx = tid + 256 * i;
      int key = idx >> 5, c4 = idx & 31;
      float4 f = *(const float4*)(V + ((size_t)kb * 64 + key) * DVD + 4 * c4);
      *(float4*)&Vf[key][4 * c4] = f;
    }
    __syncthreads();
#pragma unroll
    for (int j = 0; j < 4; ++j) {
      int s = tid + 256 * j;
      int dv = s >> 3, c = s & 7;
      uint4 d;
      uint32_t* dw = (uint32_t*)&d;
#pragma unroll
      for (int w = 0; w < 4; ++w) {
        int k0 = 8 * c + 2 * w;
        dw[w] = bf16rne(Vf[k0][dv]) | (bf16rne(Vf[k0 + 1][dv]) << 16);
      }
      size_t off = (size_t)kb * 16384 + (size_t)dv * 128 + (size_t)((c ^ (dv & 7)) << 4);
      *(uint4*)(Vtswz + off) = d;
    }
    __syncthreads();
  } else {
    uint4* m4 = (uint4*)maskT;
    int i0 = (vb - 640) * 256 + tid;
    uint4 z = {0, 0, 0, 0};
#pragma unroll
    for (int j = 0; j < 16; ++j) m4[i0 + j * 32768] = z;
  }
}

// ====================== fused cooperative kernel ======================
__global__ __launch_bounds__(256, 3) void fused_kernel(
    const float* __restrict__ Q, const float* __restrict__ K,
    const float* __restrict__ V, const int* __restrict__ mr,
    const int* __restrict__ mc, int nmask, uint8_t* __restrict__ Kswz,
    uint8_t* __restrict__ Vtswz, unsigned int* __restrict__ maskT,
    __fp16* __restrict__ Opart, float* __restrict__ lsum,
    float* __restrict__ out, int nsplit) {
  cg::grid_group grid = cg::this_grid();
  const int bid = blockIdx.x;
  const int tid = threadIdx.x;
  const int nthr = gridDim.x * 256;
  __shared__ uint8_t smem[40960];

  // P0: conv + mask clear (grid-stride over 768 virtual blocks)
  for (int vb = bid; vb < 768; vb += gridDim.x)
    conv_vblock(vb, tid, K, V, Kswz, Vtswz, maskT, smem);
  __threadfence();
  grid.sync();

  // P1: mask scatter
  for (int i = bid * 256 + tid; i < nmask; i += nthr) {
    int r = mr[i], c = mc[i];
    size_t w = ((size_t)(c >> 6) * NQ + r) * 2 + ((c >> 5) & 1);
    atomicOr(&maskT[w], 1u << (c & 31));
  }
  __threadfence();
  grid.sync();

  // P2: attention; grid == 64*nsplit exactly
  {
    const int span = bid % nsplit;
    const int qblk = bid / nsplit;
    const int base = 128 / nsplit;
    const int rem = 128 - base * nsplit;
    const int niter = base + (span < rem ? 1 : 0);
    const int kb0 = span * base + (span < rem ? span : rem);
    AttnPtrs P = {Q, Kswz, Vtswz, maskT, Opart, lsum};
    attn_body(P, smem, tid, qblk, span, kb0, niter);
  }
  __threadfence();
  grid.sync();

  // P3: merge
  for (int idx = bid * 256 + tid; idx < NQ * DVD / 4; idx += nthr) {
    int row = idx >> 5, c4 = idx & 31;
    float den = 0.f;
    f32x4 o = (f32x4)0.f;
    for (int p = 0; p < nsplit; ++p) {
      den += lsum[(size_t)p * NQ + row];
      uint2 h = *(const uint2*)(Opart + ((size_t)p * NQ + row) * DVD + 4 * c4);
      H2U a, b;
      a.u = h.x; b.u = h.y;
      o[0] += (float)a.h[0]; o[1] += (float)a.h[1];
      o[2] += (float)b.h[0]; o[3] += (float)b.h[1];
    }
    o *= (1.f / den);
    ((f32x4*)out)[idx] = o;
  }
}

// ====================== fallback kernels (R9, proven) ======================
__global__ __launch_bounds__(256) void conv_scatter_kernel(
    const float* __restrict__ K, const float* __restrict__ V,
    uint8_t* __restrict__ Kswz, uint8_t* __restrict__ Vtswz,
    const int* __restrict__ mr, const int* __restrict__ mc, int nmask,
    unsigned int* __restrict__ maskT) {
  __shared__ uint8_t smem[40960];
  int b = blockIdx.x;
  int tid = threadIdx.x;
  if (b < 640) {
    conv_vblock(b, tid, K, V, Kswz, Vtswz, maskT, smem);  // mask cleared by memset
  } else {
    size_t i = (size_t)(b - 640) * 256 + tid;
    if (i < (size_t)nmask) {
      int r = mr[i], c = mc[i];
      size_t w = ((size_t)(c >> 6) * NQ + r) * 2 + ((c >> 5) & 1);
      atomicOr(&maskT[w], 1u << (c & 31));
    }
  }
}

__global__ __launch_bounds__(256, 3) void attn_kernel(
    const float* __restrict__ Q, const uint8_t* __restrict__ Kswz,
    const uint8_t* __restrict__ Vtswz, const unsigned int* __restrict__ maskT,
    __fp16* __restrict__ Opart, float* __restrict__ lsum) {
  __shared__ uint8_t smem[40960];
  const int bid = blockIdx.x;
  const int span = bid % 12;
  const int qblk = bid / 12;
  const int niter = (span < 8) ? 11 : 10;
  const int kb0 = (span < 8) ? span * 11 : 88 + (span - 8) * 10;
  AttnPtrs P = {Q, Kswz, Vtswz, maskT, Opart, lsum};
  attn_body(P, smem, threadIdx.x, qblk, span, kb0, niter);
}

__global__ __launch_bounds__(256) void merge_kernel(const __fp16* __restrict__ Opart,
                                                    const float* __restrict__ lsum,
                                                    float* __restrict__ out) {
  int idx = blockIdx.x * 256 + threadIdx.x;
  int row = idx >> 5, c4 = idx & 31;
  float den = 0.f;
  f32x4 o = (f32x4)0.f;
#pragma unroll
  for (int p = 0; p < 12; ++p) {
    den += lsum[(size_t)p * NQ + row];
    uint2 h = *(const uint2*)(Opart + ((size_t)p * NQ + row) * DVD + 4 * c4);
    H2U a, b;
    a.u = h.x; b.u = h.y;
    o[0] += (float)a.h[0]; o[1] += (float)a.h[1];
    o[2] += (float)b.h[0]; o[3] += (float)b.h[1];
  }
  o *= (1.f / den);
  ((f32x4*)out)[idx] = o;
}

extern "C" void kernel_launch(void* const* d_in, const int* in_sizes, int n_in,
                              void* d_out, int out_size, void* d_ws, size_t ws_size,
                              hipStream_t stream) {
  const float* Q = (const float*)d_in[0];
  const float* K = (const float*)d_in[1];
  const float* V = (const float*)d_in[2];
  const int* mr = (const int*)d_in[3];
  const int* mc = (const int*)d_in[4];
  int nmask = in_sizes[3];

  uint8_t* ws = (uint8_t*)d_ws;
  unsigned int* maskT = (unsigned int*)ws;
  uint8_t* Kswz = ws + OFF_K;
  uint8_t* Vtswz = ws + OFF_V;
  __fp16* Opart = (__fp16*)(ws + OFF_OP);
  float* lsum = (float*)(ws + OFF_L);
  float* outp = (float*)d_out;

  // ---- occupancy-guarded cooperative path (host-only query; capture-safe)
  int occ = 0;
  hipError_t qe = hipOccupancyMaxActiveBlocksPerMultiprocessor(&occ, fused_kernel, 256, 0);
  int nsplit = 0;
  if (qe == hipSuccess) {
    if (occ >= 3) nsplit = 12;        // grid 768 = 256 CU x 3
    else if (occ == 2) nsplit = 8;    // grid 512 = 256 CU x 2
  }
  if (nsplit) {
    int grid = NQB * nsplit;
    void* args[] = {(void*)&Q,     (void*)&K,     (void*)&V,    (void*)&mr,
                    (void*)&mc,    (void*)&nmask, (void*)&Kswz, (void*)&Vtswz,
                    (void*)&maskT, (void*)&Opart, (void*)&lsum, (void*)&outp,
                    (void*)&nsplit};
    hipError_t le = hipLaunchCooperativeKernel((const void*)fused_kernel, dim3(grid),
                                               dim3(256), args, 0, stream);
    if (le == hipSuccess) {
      // zero unused lsum/Opart spans? merge loops only over nsplit -> not needed
      return;
    }
  }

  // ---- fallback: proven R9 4-dispatch path (nsplit fixed 12)
  hipMemsetAsync(maskT, 0, SZ_MASK, stream);
  conv_scatter_kernel<<<640 + (nmask + 255) / 256, 256, 0, stream>>>(
      K, V, Kswz, Vtswz, mr, mc, nmask, maskT);
  attn_kernel<<<NQB * 12, 256, 0, stream>>>(Q, Kswz, Vtswz, maskT, Opart, lsum);
  merge_kernel<<<NQ * DVD / 4 / 256, 256, 0, stream>>>(Opart, lsum, (float*)d_out);
}

// Round 12
// 166.738 us; speedup vs baseline: 1.0213x; 1.0213x over previous
//
#include <hip/hip_runtime.h>
#include <stdint.h>

// N=M=8192, D=DV=128, fp32 in/out. bf16-MFMA flash attention.
// R12: BK=32 double-buffered LDS, ONE barrier/iter (loads in flight across the
//      whole compute phase), mask prefetch one iter ahead. 4-dispatch structure
//      (R11 proved fusion is worth exactly zero).
#define NQ 8192
#define NM 8192
#define DD 128
#define DVD 128
#define NQB 64                 // 8192/128 q-blocks
#define NSPLIT 12              // spans 0-3: 22 kb32, spans 4-11: 21 kb32 (=256)

typedef float f32x4 __attribute__((ext_vector_type(4)));
typedef short s16x8 __attribute__((ext_vector_type(8)));
typedef __fp16 fp16x2 __attribute__((ext_vector_type(2)));
union FragU { uint32_t u[4]; s16x8 v; };
union H2U { fp16x2 h; uint32_t u; };

__device__ __forceinline__ uint32_t bf16rne(float x) {
  uint32_t u = __float_as_uint(x);
  return (u + 0x7FFFu + ((u >> 16) & 1u)) >> 16;
}
__device__ __forceinline__ uint32_t pk2(float a, float b) {
  return __builtin_amdgcn_perm(__float_as_uint(b) + 0x8000u,
                               __float_as_uint(a) + 0x8000u, 0x07060302u);
}
__device__ __forceinline__ void glds16(const void* g, void* l) {
  __builtin_amdgcn_global_load_lds((const __attribute__((address_space(1))) uint32_t*)g,
                                   (__attribute__((address_space(3))) uint32_t*)l, 16, 0, 0);
}

// ---- workspace layout (bytes) ----
#define SZ_MASK ((size_t)(NM / 32) * NQ * 4)   // 8 MB: uint32 per (kb32, q)
#define OFF_K   (SZ_MASK)
#define SZ_KB   ((size_t)NM * DD * 2)          // 2 MB swizzled bf16 K tiles (8KB/32 keys)
#define OFF_V   (OFF_K + SZ_KB)                // 2 MB swizzled bf16 V^T tiles
#define OFF_OP  (OFF_V + SZ_KB)
#define SZ_OPH  ((size_t)NQ * DVD * 2)         // fp16 partial O per span
#define OFF_L   (OFF_OP + (size_t)NSPLIT * SZ_OPH)

// One dispatch: K-swizzle (512 blocks) + V^T-swizzle (256) + mask scatter (rest).
// Mask cleared by memset node before this dispatch.
__global__ __launch_bounds__(256) void conv_scatter_kernel(
    const float* __restrict__ K, const float* __restrict__ V,
    uint8_t* __restrict__ Kswz, uint8_t* __restrict__ Vtswz,
    const int* __restrict__ mr, const int* __restrict__ mc, int nmask,
    unsigned int* __restrict__ maskT) {
  __shared__ float Vf[32][132];
  int b = blockIdx.x;
  int tid = threadIdx.x;
  if (b < 512) {  // ---- K: tile(32 keys)=8KB; row=key(256B,16 chunks), chunk^=(key&15)
    int t = b * 256 + tid;
    int key = t >> 4, c = t & 15;
    const float* s = K + (size_t)key * DD + 8 * c;
    float4 a = *(const float4*)s, bb = *(const float4*)(s + 4);
    uint4 d;
    d.x = bf16rne(a.x) | (bf16rne(a.y) << 16);
    d.y = bf16rne(a.z) | (bf16rne(a.w) << 16);
    d.z = bf16rne(bb.x) | (bf16rne(bb.y) << 16);
    d.w = bf16rne(bb.z) | (bf16rne(bb.w) << 16);
    size_t off = (size_t)(key >> 5) * 8192 + (size_t)(key & 31) * 256 +
                 (size_t)((c ^ (key & 15)) << 4);
    *(uint4*)(Kswz + off) = d;
  } else if (b < 768) {  // ---- V^T: tile=[128 dv][32 keys] (64B rows, 4 chunks), chunk^=(dv&3)
    int kb = b - 512;    // 256 tiles
#pragma unroll
    for (int i = 0; i < 4; ++i) {
      int idx = tid + 256 * i;
      int key = idx >> 5, c4 = idx & 31;
      float4 f = *(const float4*)(V + ((size_t)kb * 32 + key) * DVD + 4 * c4);
      *(float4*)&Vf[key][4 * c4] = f;
    }
    __syncthreads();
#pragma unroll
    for (int j = 0; j < 2; ++j) {
      int s = tid + 256 * j;           // 512 slots: dv(128) x chunk(4)
      int dv = s >> 2, c = s & 3;
      uint4 d;
      uint32_t* dw = (uint32_t*)&d;
#pragma unroll
      for (int w = 0; w < 4; ++w) {
        int k0 = 8 * c + 2 * w;
        dw[w] = bf16rne(Vf[k0][dv]) | (bf16rne(Vf[k0 + 1][dv]) << 16);
      }
      size_t off = (size_t)kb * 8192 + (size_t)dv * 64 + (size_t)((c ^ (dv & 3)) << 4);
      *(uint4*)(Vtswz + off) = d;
    }
  } else {  // ---- scatter
    size_t i = (size_t)(b - 768) * 256 + tid;
    if (i < (size_t)nmask) {
      int r = mr[i], c = mc[i];
      atomicOr(&maskT[(size_t)(c >> 5) * NQ + r], 1u << (c & 31));
    }
  }
}

__global__ __launch_bounds__(256, 3) void attn_kernel(
    const float* __restrict__ Q, const uint8_t* __restrict__ Kswz,
    const uint8_t* __restrict__ Vtswz, const unsigned int* __restrict__ maskT,
    __fp16* __restrict__ Opart, float* __restrict__ lsum) {
  const int bid = blockIdx.x;
  const int span = bid % NSPLIT;            // grid = 768 = one resident round
  const int qblk = bid / NSPLIT;
  const int niter = (span < 4) ? 22 : 21;   // 4*22 + 8*21 = 256 kb32
  const int kb0 = (span < 4) ? span * 22 : 88 + (span - 4) * 21;

  const int tid = threadIdx.x;
  const int wid = tid >> 6, lane = tid & 63;
  const int g = lane >> 4, qi = lane & 15;
  const int qw = qblk * 128 + wid * 32;     // wave's 32 q rows

  // LDS: K dbuf 2x8K | V dbuf 2x8K | Psc 4K  = 36864 B -> 3 WG/CU
  __shared__ uint8_t smem[36864];
  uint8_t* Klds = smem;
  uint8_t* Vlds = smem + 16384;
  uint32_t* Psc = (uint32_t*)(smem + 32768);  // [4 waves][16 qi][16 dwords]

  const float SC = 0.08838834764831845f * 1.4426950408889634f;  // 1/sqrt(128)*log2e

  // ---- resident Q B-frags (scale folded)
  s16x8 qfrag[2][4];
#pragma unroll
  for (int qt = 0; qt < 2; ++qt)
#pragma unroll
    for (int ks = 0; ks < 4; ++ks) {
      const float* qs = Q + (size_t)(qw + 16 * qt + qi) * DD + 32 * ks + 8 * g;
      float4 a = *(const float4*)qs, b = *(const float4*)(qs + 4);
      FragU fu;
      fu.u[0] = bf16rne(a.x * SC) | (bf16rne(a.y * SC) << 16);
      fu.u[1] = bf16rne(a.z * SC) | (bf16rne(a.w * SC) << 16);
      fu.u[2] = bf16rne(b.x * SC) | (bf16rne(b.y * SC) << 16);
      fu.u[3] = bf16rne(b.z * SC) | (bf16rne(b.w * SC) << 16);
      qfrag[qt][ks] = fu.v;
    }

  f32x4 accO[8][2];
#pragma unroll
  for (int dt = 0; dt < 8; ++dt)
#pragma unroll
    for (int qt = 0; qt < 2; ++qt) accO[dt][qt] = (f32x4)0.f;
  f32x4 accL[2] = {(f32x4)0.f, (f32x4)0.f};
  const f32x4 z4 = (f32x4)0.f;

  FragU onesu;
  onesu.u[0] = onesu.u[1] = onesu.u[2] = onesu.u[3] = 0x3F803F80u;
  const s16x8 onesfrag = onesu.v;

  // ---- loop-invariant LDS pointers (dbuf adds par*512 s16x8 units = 8192 B)
  const s16x8* kp0[4];
#pragma unroll
  for (int ks = 0; ks < 4; ++ks)
    kp0[ks] = (const s16x8*)Klds + qi * 16 + ((g + 4 * ks) ^ qi);
  const s16x8* vp0 = (const s16x8*)Vlds + qi * 4 + (g ^ (qi & 3));
  // Psc: row qi of 16 dwords; b64 granule wg stored at wg^(qi&7)
  uint32_t* pw = Psc + (wid * 16 + qi) * 16;
  uint32_t* wr[2];
#pragma unroll
  for (int kt = 0; kt < 2; ++kt) wr[kt] = &pw[2 * ((4 * kt + g) ^ (qi & 7))];
  const uint32_t* rd[2];
#pragma unroll
  for (int hb = 0; hb < 2; ++hb) rd[hb] = &pw[2 * ((2 * g + hb) ^ (qi & 7))];

  // ---- running global pointers
  const uint8_t* ktp = Kswz + (size_t)kb0 * 8192 + (size_t)tid * 16;
  const uint8_t* vtp = Vtswz + (size_t)kb0 * 8192 + (size_t)tid * 16;
  uint8_t* kld = Klds + wid * 1024;
  uint8_t* vld = Vlds + wid * 1024;
  const uint32_t* mq = maskT + (size_t)kb0 * NQ + qw + qi;  // +16 for qt=1

  // ---- prologue: stage tile 0 into buf0; preload masks for it 0
  {
    glds16(ktp, kld);
    glds16(ktp + 4096, kld + 4096);
    glds16(vtp, vld);
    glds16(vtp + 4096, vld + 4096);
    ktp += 8192; vtp += 8192;
  }
  uint32_t wmc0 = mq[0], wmc1 = mq[16];
  const uint32_t* mqn = mq + NQ;  // kb0+1 always valid (niter >= 21)

  for (int it = 0; it < niter; ++it) {
    // ONE barrier per iter. Its vmcnt(0) drain targets loads issued one full
    // iteration ago -> near-free. Also guarantees all waves done reading the
    // buffer about to be overwritten below.
    __syncthreads();
    const int par = it & 1;
    const int nxt = it + 1 < niter;
    if (nxt) {  // stage tile it+1 into other buffer; in flight during compute
      uint8_t* kldn = kld + (par ? 0 : 8192);
      uint8_t* vldn = vld + (par ? 0 : 8192);
      glds16(ktp, kldn);
      glds16(ktp + 4096, kldn + 4096);
      glds16(vtp, vldn);
      glds16(vtp + 4096, vldn + 4096);
      ktp += 8192; vtp += 8192;
    }
    // prefetch masks for it+1 (cold loads; consumed next iter)
    uint32_t wmn0 = mqn[0], wmn1 = mqn[16];
    if (nxt) mqn += NQ;

    // ---- S^T = K . Q^T : 16 mfma, 8 ds_read_b128
    const int kofs = par * 512;
    f32x4 sf[2][2];
#pragma unroll
    for (int kt = 0; kt < 2; ++kt) {
      {
        s16x8 kf = kp0[0][kofs + kt * 256];
        sf[0][kt] = __builtin_amdgcn_mfma_f32_16x16x32_bf16(kf, qfrag[0][0], z4, 0, 0, 0);
        sf[1][kt] = __builtin_amdgcn_mfma_f32_16x16x32_bf16(kf, qfrag[1][0], z4, 0, 0, 0);
      }
#pragma unroll
      for (int ks = 1; ks < 4; ++ks) {
        s16x8 kf = kp0[ks][kofs + kt * 256];
        sf[0][kt] = __builtin_amdgcn_mfma_f32_16x16x32_bf16(kf, qfrag[0][ks], sf[0][kt], 0, 0, 0);
        sf[1][kt] = __builtin_amdgcn_mfma_f32_16x16x32_bf16(kf, qfrag[1][ks], sf[1][kt], 0, 0, 0);
      }
    }

    // ---- rare mask apply
    if (__ballot((wmc0 | wmc1) != 0)) {
#pragma unroll
      for (int qt = 0; qt < 2; ++qt) {
        uint32_t wm = qt ? wmc1 : wmc0;
#pragma unroll
        for (int kt = 0; kt < 2; ++kt)
#pragma unroll
          for (int r = 0; r < 4; ++r) {
            int kl = 16 * kt + 4 * g + r;
            if ((wm >> kl) & 1u) sf[qt][kt][r] = -3.0e38f;
          }
      }
    }
    wmc0 = wmn0; wmc1 = wmn1;

    // ---- P = exp2(sf) (raw v_exp), perm-pack, C->B via per-wave LDS row
    s16x8 pfrag[2];
#pragma unroll
    for (int qt = 0; qt < 2; ++qt) {
#pragma unroll
      for (int kt = 0; kt < 2; ++kt) {
        float p0 = __builtin_amdgcn_exp2f(sf[qt][kt][0]);
        float p1 = __builtin_amdgcn_exp2f(sf[qt][kt][1]);
        float p2 = __builtin_amdgcn_exp2f(sf[qt][kt][2]);
        float p3 = __builtin_amdgcn_exp2f(sf[qt][kt][3]);
        uint2 pk;
        pk.x = pk2(p0, p1);
        pk.y = pk2(p2, p3);
        *(uint2*)wr[kt] = pk;  // granule 4kt+g (keys 16kt+4g..+3)
      }
      // same-wave LDS in-order: reads see this wave's writes (qt-sequential reuse)
      uint2 a0 = *(const uint2*)rd[0];  // keys 8g..8g+3
      uint2 b0 = *(const uint2*)rd[1];  // keys 8g+4..8g+7
      FragU pf;
      pf.u[0] = a0.x; pf.u[1] = a0.y; pf.u[2] = b0.x; pf.u[3] = b0.y;
      pfrag[qt] = pf.v;
    }

    // ---- l += colsum(P)
    accL[0] = __builtin_amdgcn_mfma_f32_16x16x32_bf16(onesfrag, pfrag[0], accL[0], 0, 0, 0);
    accL[1] = __builtin_amdgcn_mfma_f32_16x16x32_bf16(onesfrag, pfrag[1], accL[1], 0, 0, 0);

    // ---- O^T += V^T . P^T : 16 mfma, 8 ds_read_b128
#pragma unroll
    for (int dt = 0; dt < 8; ++dt) {
      s16x8 vf = vp0[kofs + dt * 64];
      accO[dt][0] = __builtin_amdgcn_mfma_f32_16x16x32_bf16(vf, pfrag[0], accO[dt][0], 0, 0, 0);
      accO[dt][1] = __builtin_amdgcn_mfma_f32_16x16x32_bf16(vf, pfrag[1], accO[dt][1], 0, 0, 0);
    }
  }

  // ---- epilogue: fp16 unnormalized O partial + per-row l
#pragma unroll
  for (int qt = 0; qt < 2; ++qt) {
    int q = qw + 16 * qt + qi;
#pragma unroll
    for (int dt = 0; dt < 8; ++dt) {
      H2U h0, h1;
      h0.h = __builtin_amdgcn_cvt_pkrtz(accO[dt][qt][0], accO[dt][qt][1]);
      h1.h = __builtin_amdgcn_cvt_pkrtz(accO[dt][qt][2], accO[dt][qt][3]);
      uint2 st = {h0.u, h1.u};
      *(uint2*)(Opart + ((size_t)span * NQ + q) * DVD + 16 * dt + 4 * g) = st;
    }
    if (g == 0) lsum[(size_t)span * NQ + q] = accL[qt][0];
  }
}

__global__ __launch_bounds__(256) void merge_kernel(const __fp16* __restrict__ Opart,
                                                    const float* __restrict__ lsum,
                                                    float* __restrict__ out) {
  int idx = blockIdx.x * 256 + threadIdx.x;
  int row = idx >> 5, c4 = idx & 31;
  float den = 0.f;
  f32x4 o = (f32x4)0.f;
#pragma unroll
  for (int p = 0; p < NSPLIT; ++p) {
    den += lsum[(size_t)p * NQ + row];
    uint2 h = *(const uint2*)(Opart + ((size_t)p * NQ + row) * DVD + 4 * c4);
    H2U a, b;
    a.u = h.x; b.u = h.y;
    o[0] += (float)a.h[0]; o[1] += (float)a.h[1];
    o[2] += (float)b.h[0]; o[3] += (float)b.h[1];
  }
  o *= (1.f / den);
  ((f32x4*)out)[idx] = o;
}

extern "C" void kernel_launch(void* const* d_in, const int* in_sizes, int n_in,
                              void* d_out, int out_size, void* d_ws, size_t ws_size,
                              hipStream_t stream) {
  const float* Q = (const float*)d_in[0];
  const float* K = (const float*)d_in[1];
  const float* V = (const float*)d_in[2];
  const int* mr = (const int*)d_in[3];
  const int* mc = (const int*)d_in[4];
  int nmask = in_sizes[3];

  uint8_t* ws = (uint8_t*)d_ws;
  unsigned int* maskT = (unsigned int*)ws;
  uint8_t* Kswz = ws + OFF_K;
  uint8_t* Vtswz = ws + OFF_V;
  __fp16* Opart = (__fp16*)(ws + OFF_OP);
  float* lsum = (float*)(ws + OFF_L);

  hipMemsetAsync(maskT, 0, SZ_MASK, stream);
  conv_scatter_kernel<<<768 + (nmask + 255) / 256, 256, 0, stream>>>(
      K, V, Kswz, Vtswz, mr, mc, nmask, maskT);
  attn_kernel<<<NQB * NSPLIT, 256, 0, stream>>>(Q, Kswz, Vtswz, maskT, Opart, lsum);
  merge_kernel<<<NQ * DVD / 4 / 256, 256, 0, stream>>>(Opart, lsum, (float*)d_out);
}